// Round 1
// baseline (1285.866 us; speedup 1.0000x reference)
//
#include <hip/hip_runtime.h>

#define N_NODES 50000
#define N_EDGES 1600000
#define ET (N_EDGES + N_NODES)   // edges + self-loops
#define DF 128                   // feature / hidden dim
#define SLOPE 0.2f

// ---------------------------------------------------------------------------
// Dual GEMM: outL = X @ Wl, outR = X @ Wr.  X: [M,128], W: [128,128].
// Tile 64 rows x 64 cols, 256 threads, 4x4 micro-tile, BK=16.
// blockIdx.y in [0,4): 0,1 -> Wl cols 0-63/64-127 ; 2,3 -> Wr.
// ---------------------------------------------------------------------------
__global__ __launch_bounds__(256) void gemm_dual(
    const float* __restrict__ X,
    const float* __restrict__ Wl, const float* __restrict__ Wr,
    float* __restrict__ outL, float* __restrict__ outR, int M)
{
    const int which = blockIdx.y;
    const float* W = (which < 2) ? Wl : Wr;
    float* out = (which < 2) ? outL : outR;
    const int cb = (which & 1) * 64;

    __shared__ float xs[16][68];   // x tile transposed: xs[k][row] (stride 68: 16B-aligned rows, no 4-way bank conflict)
    __shared__ float wsh[16][68];  // w tile: wsh[k][col]

    const int t  = threadIdx.x;
    const int tx = t & 15, ty = t >> 4;
    const int row0 = blockIdx.x * 64;

    float acc[4][4];
#pragma unroll
    for (int i = 0; i < 4; i++)
#pragma unroll
        for (int j = 0; j < 4; j++) acc[i][j] = 0.f;

    const int lr = t >> 2;        // 0..63 : row within tile for x load
    const int lk = (t & 3) * 4;   // k quad for x load
    const int wk = t >> 4;        // 0..15 : k for W load
    const int wc = (t & 15) * 4;  // col quad for W load

    for (int kb = 0; kb < 128; kb += 16) {
        int xrw = row0 + lr; if (xrw >= M) xrw = M - 1;   // clamp; store is guarded
        float4 xv = *(const float4*)(X + (size_t)xrw * DF + kb + lk);
        xs[lk + 0][lr] = xv.x; xs[lk + 1][lr] = xv.y;
        xs[lk + 2][lr] = xv.z; xs[lk + 3][lr] = xv.w;

        float4 wv = *(const float4*)(W + (size_t)(kb + wk) * DF + cb + wc);
        *(float4*)(&wsh[wk][wc]) = wv;
        __syncthreads();
#pragma unroll
        for (int kk = 0; kk < 16; kk++) {
            float4 a = *(const float4*)(&xs[kk][ty * 4]);
            float4 b = *(const float4*)(&wsh[kk][tx * 4]);
            float av[4] = {a.x, a.y, a.z, a.w};
            float bv[4] = {b.x, b.y, b.z, b.w};
#pragma unroll
            for (int i = 0; i < 4; i++)
#pragma unroll
                for (int j = 0; j < 4; j++)
                    acc[i][j] += av[i] * bv[j];
        }
        __syncthreads();
    }
#pragma unroll
    for (int i = 0; i < 4; i++) {
        int r = row0 + ty * 4 + i;
        if (r < M) {
            float4 v = make_float4(acc[i][0], acc[i][1], acc[i][2], acc[i][3]);
            *(float4*)(out + (size_t)r * DF + cb + tx * 4) = v;
        }
    }
}

// ---------------------------------------------------------------------------
// CSR build over dst (layer-invariant): histogram -> scan -> scatter
// ---------------------------------------------------------------------------
__global__ __launch_bounds__(256) void hist_kernel(const int* __restrict__ ei,
                                                   int* __restrict__ counts)
{
    int eid = blockIdx.x * 256 + threadIdx.x;
    if (eid >= ET) return;
    int dst = (eid < N_EDGES) ? ei[N_EDGES + eid] : (eid - N_EDGES);
    atomicAdd(counts + dst, 1);
}

__global__ __launch_bounds__(1024) void scan_kernel(const int* __restrict__ counts,
                                                    int* __restrict__ row_ptr,
                                                    int* __restrict__ cursor)
{
    __shared__ int sums[1024];
    const int tid = threadIdx.x;
    const int chunk = (N_NODES + 1023) / 1024;   // 49
    int lo = tid * chunk, hi = lo + chunk;
    if (hi > N_NODES) hi = N_NODES;
    if (lo > N_NODES) lo = N_NODES;
    int s = 0;
    for (int i = lo; i < hi; i++) s += counts[i];
    sums[tid] = s;
    __syncthreads();
    for (int off = 1; off < 1024; off <<= 1) {
        int v = (tid >= off) ? sums[tid - off] : 0;
        __syncthreads();
        sums[tid] += v;
        __syncthreads();
    }
    int base = sums[tid] - s;   // exclusive prefix
    for (int i = lo; i < hi; i++) {
        int c = counts[i];
        row_ptr[i] = base;
        cursor[i]  = base;
        base += c;
    }
    if (tid == 1023) row_ptr[N_NODES] = ET;
}

__global__ __launch_bounds__(256) void scatter_kernel(const int* __restrict__ ei,
                                                      int* __restrict__ cursor,
                                                      int* __restrict__ csr_src,
                                                      int* __restrict__ csr_eid)
{
    int eid = blockIdx.x * 256 + threadIdx.x;
    if (eid >= ET) return;
    int src, dst;
    if (eid < N_EDGES) { src = ei[eid]; dst = ei[N_EDGES + eid]; }
    else               { src = dst = eid - N_EDGES; }
    int pos = atomicAdd(cursor + dst, 1);
    csr_src[pos] = src;
    csr_eid[pos] = eid;
}

// ---------------------------------------------------------------------------
// Pass A: per-edge attention logits -> ex = exp(e) per head.
// Half-wave (32 lanes) per edge; lane covers 4 channels (float4); head = li/8.
// ---------------------------------------------------------------------------
__global__ __launch_bounds__(256) void edge_scores(
    const float* __restrict__ xl, const float* __restrict__ xr,
    const int* __restrict__ ei, const float* __restrict__ att,
    float* __restrict__ ex)
{
    int t = threadIdx.x;
    int wave = t >> 6, l = t & 63;
    int sub = l >> 5, li = l & 31;
    long long eid = (long long)blockIdx.x * 8 + wave * 2 + sub;
    if (eid >= ET) return;
    int src, dst;
    if (eid < N_EDGES) { src = ei[eid]; dst = ei[N_EDGES + eid]; }
    else               { src = dst = (int)(eid - N_EDGES); }
    int c0 = li * 4;
    float4 a  = *(const float4*)(xl + (size_t)src * DF + c0);
    float4 b  = *(const float4*)(xr + (size_t)dst * DF + c0);
    float4 at = *(const float4*)(att + c0);   // att flat [4*32] == global channel index
    float m0 = a.x + b.x, m1 = a.y + b.y, m2 = a.z + b.z, m3 = a.w + b.w;
    m0 = m0 > 0.f ? m0 : SLOPE * m0;
    m1 = m1 > 0.f ? m1 : SLOPE * m1;
    m2 = m2 > 0.f ? m2 : SLOPE * m2;
    m3 = m3 > 0.f ? m3 : SLOPE * m3;
    float p = m0 * at.x + m1 * at.y + m2 * at.z + m3 * at.w;
    // reduce within 8-lane head group (stays inside the 32-lane sub-edge)
    p += __shfl_xor(p, 1);
    p += __shfl_xor(p, 2);
    p += __shfl_xor(p, 4);
    if ((li & 7) == 0)
        ex[(size_t)eid * 4 + (li >> 3)] = expf(p);
}

// ---------------------------------------------------------------------------
// Pass B: one wave per dst node. acc = sum(ex * xl[src]); den = sum(ex);
// out = relu(acc/(den+1e-16) + bias). Lane covers 2 channels; head = l/16.
// ---------------------------------------------------------------------------
__global__ __launch_bounds__(256) void aggregate(
    const float* __restrict__ xl, const float* __restrict__ ex,
    const int* __restrict__ row_ptr, const int* __restrict__ csr_src,
    const int* __restrict__ csr_eid, const float* __restrict__ bias,
    float* __restrict__ out)
{
    int t = threadIdx.x;
    int wave = t >> 6, l = t & 63;
    int n = blockIdx.x * 4 + wave;
    if (n >= N_NODES) return;
    int beg = row_ptr[n], end = row_ptr[n + 1];
    int h = l >> 4;
    float acc0 = 0.f, acc1 = 0.f, den = 0.f;
    for (int i = beg; i < end; i++) {
        int s   = csr_src[i];
        int eid = csr_eid[i];
        float exv = ex[(size_t)eid * 4 + h];
        float2 v = *(const float2*)(xl + (size_t)s * DF + 2 * l);
        acc0 += exv * v.x;
        acc1 += exv * v.y;
        den  += exv;
    }
    float inv = 1.f / (den + 1e-16f);
    float2 bv = *(const float2*)(bias + 2 * l);
    float o0 = fmaxf(acc0 * inv + bv.x, 0.f);
    float o1 = fmaxf(acc1 * inv + bv.y, 0.f);
    *(float2*)(out + (size_t)n * DF + 2 * l) = make_float2(o0, o1);
}

// ---------------------------------------------------------------------------
extern "C" void kernel_launch(void* const* d_in, const int* in_sizes, int n_in,
                              void* d_out, int out_size, void* d_ws, size_t ws_size,
                              hipStream_t stream)
{
    (void)in_sizes; (void)n_in; (void)out_size; (void)ws_size;

    const float* x    = (const float*)d_in[0];
    const int*   ei   = (const int*)d_in[1];
    const float* W1l  = (const float*)d_in[2];
    const float* W1r  = (const float*)d_in[3];
    const float* att1 = (const float*)d_in[4];
    const float* b1   = (const float*)d_in[5];
    const float* W2l  = (const float*)d_in[6];
    const float* W2r  = (const float*)d_in[7];
    const float* att2 = (const float*)d_in[8];
    const float* b2   = (const float*)d_in[9];
    float* out = (float*)d_out;

    char* ws = (char*)d_ws;
    size_t off = 0;
    const size_t NF = (size_t)N_NODES * DF * sizeof(float);   // 25.6 MB
    float* A  = (float*)(ws + off); off += NF;                // xl
    float* B  = (float*)(ws + off); off += NF;                // xr
    float* C  = (float*)(ws + off); off += NF;                // layer-1 output h
    float* EX = (float*)(ws + off); off += (size_t)ET * 4 * sizeof(float);
    int* counts  = (int*)(ws + off); off += (size_t)N_NODES * sizeof(int);
    int* row_ptr = (int*)(ws + off); off += (size_t)(N_NODES + 1) * sizeof(int);
    int* cursor  = (int*)(ws + off); off += (size_t)N_NODES * sizeof(int);
    int* csr_src = (int*)(ws + off); off += (size_t)ET * sizeof(int);
    int* csr_eid = (int*)(ws + off); off += (size_t)ET * sizeof(int);

    // ---- CSR over dst (shared by both layers) ----
    hipMemsetAsync(counts, 0, (size_t)N_NODES * sizeof(int), stream);
    hist_kernel<<<(ET + 255) / 256, 256, 0, stream>>>(ei, counts);
    scan_kernel<<<1, 1024, 0, stream>>>(counts, row_ptr, cursor);
    scatter_kernel<<<(ET + 255) / 256, 256, 0, stream>>>(ei, cursor, csr_src, csr_eid);

    dim3 gg((N_NODES + 63) / 64, 4);

    // ---- layer 1 ----
    gemm_dual<<<gg, 256, 0, stream>>>(x, W1l, W1r, A, B, N_NODES);
    edge_scores<<<(ET + 7) / 8, 256, 0, stream>>>(A, B, ei, att1, EX);
    aggregate<<<(N_NODES + 3) / 4, 256, 0, stream>>>(A, EX, row_ptr, csr_src, csr_eid, b1, C);

    // ---- layer 2 ----
    gemm_dual<<<gg, 256, 0, stream>>>(C, W2l, W2r, A, B, N_NODES);
    edge_scores<<<(ET + 7) / 8, 256, 0, stream>>>(A, B, ei, att2, EX);
    aggregate<<<(N_NODES + 3) / 4, 256, 0, stream>>>(A, EX, row_ptr, csr_src, csr_eid, b2, out);
}

// Round 2
// 767.869 us; speedup vs baseline: 1.6746x; 1.6746x over previous
//
#include <hip/hip_runtime.h>

#define N_NODES 50000
#define N_EDGES 1600000
#define ET (N_EDGES + N_NODES)   // edges + self-loops
#define DF 128                   // feature / hidden dim
#define SLOPE 0.2f

// ---------------------------------------------------------------------------
// Dual GEMM: outL = X @ Wl, outR = X @ Wr.  X: [M,128], W: [128,128].
// Tile 64 rows x 64 cols, 256 threads, 4x4 micro-tile, BK=16.
// blockIdx.y in [0,4): 0,1 -> Wl cols 0-63/64-127 ; 2,3 -> Wr.
// ---------------------------------------------------------------------------
__global__ __launch_bounds__(256) void gemm_dual(
    const float* __restrict__ X,
    const float* __restrict__ Wl, const float* __restrict__ Wr,
    float* __restrict__ outL, float* __restrict__ outR, int M)
{
    const int which = blockIdx.y;
    const float* W = (which < 2) ? Wl : Wr;
    float* out = (which < 2) ? outL : outR;
    const int cb = (which & 1) * 64;

    __shared__ float xs[16][68];   // x tile transposed: xs[k][row]
    __shared__ float wsh[16][68];  // w tile: wsh[k][col]

    const int t  = threadIdx.x;
    const int tx = t & 15, ty = t >> 4;
    const int row0 = blockIdx.x * 64;

    float acc[4][4];
#pragma unroll
    for (int i = 0; i < 4; i++)
#pragma unroll
        for (int j = 0; j < 4; j++) acc[i][j] = 0.f;

    const int lr = t >> 2;        // 0..63 : row within tile for x load
    const int lk = (t & 3) * 4;   // k quad for x load
    const int wk = t >> 4;        // 0..15 : k for W load
    const int wc = (t & 15) * 4;  // col quad for W load

    for (int kb = 0; kb < 128; kb += 16) {
        int xrw = row0 + lr; if (xrw >= M) xrw = M - 1;   // clamp; store is guarded
        float4 xv = *(const float4*)(X + (size_t)xrw * DF + kb + lk);
        xs[lk + 0][lr] = xv.x; xs[lk + 1][lr] = xv.y;
        xs[lk + 2][lr] = xv.z; xs[lk + 3][lr] = xv.w;

        float4 wv = *(const float4*)(W + (size_t)(kb + wk) * DF + cb + wc);
        *(float4*)(&wsh[wk][wc]) = wv;
        __syncthreads();
#pragma unroll
        for (int kk = 0; kk < 16; kk++) {
            float4 a = *(const float4*)(&xs[kk][ty * 4]);
            float4 b = *(const float4*)(&wsh[kk][tx * 4]);
            float av[4] = {a.x, a.y, a.z, a.w};
            float bv[4] = {b.x, b.y, b.z, b.w};
#pragma unroll
            for (int i = 0; i < 4; i++)
#pragma unroll
                for (int j = 0; j < 4; j++)
                    acc[i][j] += av[i] * bv[j];
        }
        __syncthreads();
    }
#pragma unroll
    for (int i = 0; i < 4; i++) {
        int r = row0 + ty * 4 + i;
        if (r < M) {
            float4 v = make_float4(acc[i][0], acc[i][1], acc[i][2], acc[i][3]);
            *(float4*)(out + (size_t)r * DF + cb + tx * 4) = v;
        }
    }
}

// ---------------------------------------------------------------------------
// CSR build over dst (layer-invariant): histogram -> scan -> scatter
// ---------------------------------------------------------------------------
__global__ __launch_bounds__(256) void hist_kernel(const int* __restrict__ ei,
                                                   int* __restrict__ counts)
{
    int eid = blockIdx.x * 256 + threadIdx.x;
    if (eid >= ET) return;
    int dst = (eid < N_EDGES) ? ei[N_EDGES + eid] : (eid - N_EDGES);
    atomicAdd(counts + dst, 1);
}

__global__ __launch_bounds__(1024) void scan_kernel(const int* __restrict__ counts,
                                                    int* __restrict__ row_ptr,
                                                    int* __restrict__ cursor)
{
    __shared__ int sums[1024];
    const int tid = threadIdx.x;
    const int chunk = (N_NODES + 1023) / 1024;   // 49
    int lo = tid * chunk, hi = lo + chunk;
    if (hi > N_NODES) hi = N_NODES;
    if (lo > N_NODES) lo = N_NODES;
    int s = 0;
    for (int i = lo; i < hi; i++) s += counts[i];
    sums[tid] = s;
    __syncthreads();
    for (int off = 1; off < 1024; off <<= 1) {
        int v = (tid >= off) ? sums[tid - off] : 0;
        __syncthreads();
        sums[tid] += v;
        __syncthreads();
    }
    int base = sums[tid] - s;   // exclusive prefix
    for (int i = lo; i < hi; i++) {
        int c = counts[i];
        row_ptr[i] = base;
        cursor[i]  = base;
        base += c;
    }
    if (tid == 1023) row_ptr[N_NODES] = ET;
}

__global__ __launch_bounds__(256) void scatter_kernel(const int* __restrict__ ei,
                                                      int* __restrict__ cursor,
                                                      int* __restrict__ csr_src)
{
    int eid = blockIdx.x * 256 + threadIdx.x;
    if (eid >= ET) return;
    int src, dst;
    if (eid < N_EDGES) { src = ei[eid]; dst = ei[N_EDGES + eid]; }
    else               { src = dst = eid - N_EDGES; }
    int pos = atomicAdd(cursor + dst, 1);
    csr_src[pos] = src;
}

// ---------------------------------------------------------------------------
// Fused scores + softmax + aggregate: one wave per dst node.
// Lane l covers channels {2l, 2l+1}; head = l>>4 (head = channel/32).
// Per edge: load xl[src] (float2/lane), msg = xl+xr(reg), leaky, dot att,
// 16-lane xor-reduce -> head logit, e = exp, acc += e*xl, den += e.
// out = relu(acc/(den+1e-16) + bias).
// ---------------------------------------------------------------------------
__global__ __launch_bounds__(256) void fused_agg(
    const float* __restrict__ xl, const float* __restrict__ xr,
    const int* __restrict__ row_ptr, const int* __restrict__ csr_src,
    const float* __restrict__ att, const float* __restrict__ bias,
    float* __restrict__ out)
{
    int t = threadIdx.x;
    int wave = t >> 6, l = t & 63;
    int n = blockIdx.x * 4 + wave;
    if (n >= N_NODES) return;
    int beg = row_ptr[n], end = row_ptr[n + 1];

    float2 xrv = *(const float2*)(xr + (size_t)n * DF + 2 * l);
    float2 atv = *(const float2*)(att + 2 * l);

    float acc0 = 0.f, acc1 = 0.f, den = 0.f;

    for (int base = beg; base < end; base += 64) {
        int cnt = end - base; if (cnt > 64) cnt = 64;
        int my_src = 0;
        if (base + l < end) my_src = csr_src[base + l];   // coalesced batch load
        for (int j = 0; j < cnt; j++) {
            int s = __shfl(my_src, j);
            float2 v = *(const float2*)(xl + (size_t)s * DF + 2 * l);
            float m0 = v.x + xrv.x, m1 = v.y + xrv.y;
            m0 = m0 > 0.f ? m0 : SLOPE * m0;
            m1 = m1 > 0.f ? m1 : SLOPE * m1;
            float p = m0 * atv.x + m1 * atv.y;
            // reduce over the 16 lanes of this head group
            p += __shfl_xor(p, 1);
            p += __shfl_xor(p, 2);
            p += __shfl_xor(p, 4);
            p += __shfl_xor(p, 8);
            float e = __expf(p);
            acc0 += e * v.x;
            acc1 += e * v.y;
            den  += e;
        }
    }

    float inv = 1.f / (den + 1e-16f);
    float2 bv = *(const float2*)(bias + 2 * l);
    float o0 = fmaxf(acc0 * inv + bv.x, 0.f);
    float o1 = fmaxf(acc1 * inv + bv.y, 0.f);
    *(float2*)(out + (size_t)n * DF + 2 * l) = make_float2(o0, o1);
}

// ---------------------------------------------------------------------------
extern "C" void kernel_launch(void* const* d_in, const int* in_sizes, int n_in,
                              void* d_out, int out_size, void* d_ws, size_t ws_size,
                              hipStream_t stream)
{
    (void)in_sizes; (void)n_in; (void)out_size; (void)ws_size;

    const float* x    = (const float*)d_in[0];
    const int*   ei   = (const int*)d_in[1];
    const float* W1l  = (const float*)d_in[2];
    const float* W1r  = (const float*)d_in[3];
    const float* att1 = (const float*)d_in[4];
    const float* b1   = (const float*)d_in[5];
    const float* W2l  = (const float*)d_in[6];
    const float* W2r  = (const float*)d_in[7];
    const float* att2 = (const float*)d_in[8];
    const float* b2   = (const float*)d_in[9];
    float* out = (float*)d_out;

    char* ws = (char*)d_ws;
    size_t off = 0;
    const size_t NF = (size_t)N_NODES * DF * sizeof(float);   // 25.6 MB
    float* A  = (float*)(ws + off); off += NF;                // xl
    float* B  = (float*)(ws + off); off += NF;                // xr
    float* C  = (float*)(ws + off); off += NF;                // layer-1 output h
    int* counts  = (int*)(ws + off); off += (size_t)N_NODES * sizeof(int);
    int* row_ptr = (int*)(ws + off); off += (size_t)(N_NODES + 1) * sizeof(int);
    int* cursor  = (int*)(ws + off); off += (size_t)N_NODES * sizeof(int);
    int* csr_src = (int*)(ws + off); off += (size_t)ET * sizeof(int);

    // ---- CSR over dst (shared by both layers) ----
    hipMemsetAsync(counts, 0, (size_t)N_NODES * sizeof(int), stream);
    hist_kernel<<<(ET + 255) / 256, 256, 0, stream>>>(ei, counts);
    scan_kernel<<<1, 1024, 0, stream>>>(counts, row_ptr, cursor);
    scatter_kernel<<<(ET + 255) / 256, 256, 0, stream>>>(ei, cursor, csr_src);

    dim3 gg((N_NODES + 63) / 64, 4);

    // ---- layer 1 ----
    gemm_dual<<<gg, 256, 0, stream>>>(x, W1l, W1r, A, B, N_NODES);
    fused_agg<<<(N_NODES + 3) / 4, 256, 0, stream>>>(A, B, row_ptr, csr_src, att1, b1, C);

    // ---- layer 2 ----
    gemm_dual<<<gg, 256, 0, stream>>>(C, W2l, W2r, A, B, N_NODES);
    fused_agg<<<(N_NODES + 3) / 4, 256, 0, stream>>>(A, B, row_ptr, csr_src, att2, b2, out);
}

// Round 3
// 702.850 us; speedup vs baseline: 1.8295x; 1.0925x over previous
//
#include <hip/hip_runtime.h>

#define N_NODES 50000
#define N_EDGES 1600000
#define ET (N_EDGES + N_NODES)   // edges + self-loops
#define DF 128                   // feature / hidden dim
#define SLOPE 0.2f

// ---------------------------------------------------------------------------
// Dual GEMM: outL = X @ Wl, outR = X @ Wr.  X: [M,128], W: [128,128].
// Tile 64 rows x 64 cols, 256 threads, 4x4 micro-tile, BK=32 (8 barriers total).
// blockIdx.y in [0,4): 0,1 -> Wl cols 0-63/64-127 ; 2,3 -> Wr.
// ---------------------------------------------------------------------------
__global__ __launch_bounds__(256) void gemm_dual(
    const float* __restrict__ X,
    const float* __restrict__ Wl, const float* __restrict__ Wr,
    float* __restrict__ outL, float* __restrict__ outR, int M)
{
    const int which = blockIdx.y;
    const float* W = (which < 2) ? Wl : Wr;
    float* out = (which < 2) ? outL : outR;
    const int cb = (which & 1) * 64;

    __shared__ float xs[32][68];   // x tile transposed: xs[k][row]
    __shared__ float wsh[32][68];  // w tile: wsh[k][col]

    const int t  = threadIdx.x;
    const int tx = t & 15, ty = t >> 4;
    const int row0 = blockIdx.x * 64;

    float acc[4][4];
#pragma unroll
    for (int i = 0; i < 4; i++)
#pragma unroll
        for (int j = 0; j < 4; j++) acc[i][j] = 0.f;

    const int lr = t >> 2;        // 0..63 : row within tile for x load
    const int lk = (t & 3) * 8;   // k octet base for x load (0,8,16,24)
    const int wk = t >> 4;        // 0..15 : k (and k+16) for W load
    const int wc = (t & 15) * 4;  // col quad for W load

    for (int kb = 0; kb < 128; kb += 32) {
        int xrw = row0 + lr; if (xrw >= M) xrw = M - 1;   // clamp; store is guarded
        float4 xv0 = *(const float4*)(X + (size_t)xrw * DF + kb + lk);
        float4 xv1 = *(const float4*)(X + (size_t)xrw * DF + kb + lk + 4);
        xs[lk + 0][lr] = xv0.x; xs[lk + 1][lr] = xv0.y;
        xs[lk + 2][lr] = xv0.z; xs[lk + 3][lr] = xv0.w;
        xs[lk + 4][lr] = xv1.x; xs[lk + 5][lr] = xv1.y;
        xs[lk + 6][lr] = xv1.z; xs[lk + 7][lr] = xv1.w;

        float4 wv0 = *(const float4*)(W + (size_t)(kb + wk) * DF + cb + wc);
        float4 wv1 = *(const float4*)(W + (size_t)(kb + wk + 16) * DF + cb + wc);
        *(float4*)(&wsh[wk][wc])      = wv0;
        *(float4*)(&wsh[wk + 16][wc]) = wv1;
        __syncthreads();
#pragma unroll
        for (int kk = 0; kk < 32; kk++) {
            float4 a = *(const float4*)(&xs[kk][ty * 4]);
            float4 b = *(const float4*)(&wsh[kk][tx * 4]);
            float av[4] = {a.x, a.y, a.z, a.w};
            float bv[4] = {b.x, b.y, b.z, b.w};
#pragma unroll
            for (int i = 0; i < 4; i++)
#pragma unroll
                for (int j = 0; j < 4; j++)
                    acc[i][j] += av[i] * bv[j];
        }
        __syncthreads();
    }
#pragma unroll
    for (int i = 0; i < 4; i++) {
        int r = row0 + ty * 4 + i;
        if (r < M) {
            float4 v = make_float4(acc[i][0], acc[i][1], acc[i][2], acc[i][3]);
            *(float4*)(out + (size_t)r * DF + cb + tx * 4) = v;
        }
    }
}

// ---------------------------------------------------------------------------
// CSR build over dst (layer-invariant): histogram -> scan -> scatter
// ---------------------------------------------------------------------------
__global__ __launch_bounds__(256) void hist_kernel(const int* __restrict__ ei,
                                                   int* __restrict__ counts)
{
    int eid = blockIdx.x * 256 + threadIdx.x;
    if (eid >= ET) return;
    int dst = (eid < N_EDGES) ? ei[N_EDGES + eid] : (eid - N_EDGES);
    atomicAdd(counts + dst, 1);
}

__global__ __launch_bounds__(1024) void scan_kernel(const int* __restrict__ counts,
                                                    int* __restrict__ row_ptr,
                                                    int* __restrict__ cursor)
{
    __shared__ int sums[1024];
    const int tid = threadIdx.x;
    const int chunk = (N_NODES + 1023) / 1024;   // 49
    int lo = tid * chunk, hi = lo + chunk;
    if (hi > N_NODES) hi = N_NODES;
    if (lo > N_NODES) lo = N_NODES;
    int s = 0;
    for (int i = lo; i < hi; i++) s += counts[i];
    sums[tid] = s;
    __syncthreads();
    for (int off = 1; off < 1024; off <<= 1) {
        int v = (tid >= off) ? sums[tid - off] : 0;
        __syncthreads();
        sums[tid] += v;
        __syncthreads();
    }
    int base = sums[tid] - s;   // exclusive prefix
    for (int i = lo; i < hi; i++) {
        int c = counts[i];
        row_ptr[i] = base;
        cursor[i]  = base;
        base += c;
    }
    if (tid == 1023) row_ptr[N_NODES] = ET;
}

__global__ __launch_bounds__(256) void scatter_kernel(const int* __restrict__ ei,
                                                      int* __restrict__ cursor,
                                                      int* __restrict__ csr_src)
{
    int eid = blockIdx.x * 256 + threadIdx.x;
    if (eid >= ET) return;
    int src, dst;
    if (eid < N_EDGES) { src = ei[eid]; dst = ei[N_EDGES + eid]; }
    else               { src = dst = eid - N_EDGES; }
    int pos = atomicAdd(cursor + dst, 1);
    csr_src[pos] = src;
}

// ---------------------------------------------------------------------------
// Fused scores + softmax + aggregate: one wave per dst node, 2 edges/iter.
// Half-wave (32 lanes) per edge; lane covers 4 channels (float4); head = li/8.
// Per edge: load xl[src] float4, msg = xl+xr(reg), leaky, dot att,
// 8-lane xor-reduce -> head logit, e = exp, acc += e*xl, den += e.
// Cross-half combine at the end; out = relu(acc/(den+1e-16) + bias).
// ---------------------------------------------------------------------------
__global__ __launch_bounds__(256) void fused_agg(
    const float* __restrict__ xl, const float* __restrict__ xr,
    const int* __restrict__ row_ptr, const int* __restrict__ csr_src,
    const float* __restrict__ att, const float* __restrict__ bias,
    float* __restrict__ out)
{
    int t = threadIdx.x;
    int wave = t >> 6, l = t & 63;
    int sub = l >> 5, li = l & 31;          // half-wave id, lane within half
    int n = blockIdx.x * 4 + wave;
    if (n >= N_NODES) return;
    int beg = row_ptr[n], end = row_ptr[n + 1];

    const int c0 = 4 * li;
    float4 xrv = *(const float4*)(xr + (size_t)n * DF + c0);
    float4 atv = *(const float4*)(att + c0);

    float a0 = 0.f, a1 = 0.f, a2 = 0.f, a3 = 0.f, den = 0.f;

    for (int base = beg; base < end; base += 64) {
        int cnt = end - base; if (cnt > 64) cnt = 64;
        int my_src = 0;
        if (base + l < end) my_src = csr_src[base + l];   // coalesced batch load
        int npair = (cnt + 1) >> 1;
        for (int j = 0; j < npair; j++) {
            int eidx = 2 * j + sub;                       // edge slot for my half
            int s = __shfl(my_src, eidx);
            float4 v = *(const float4*)(xl + (size_t)s * DF + c0);
            float m0 = v.x + xrv.x, m1 = v.y + xrv.y;
            float m2 = v.z + xrv.z, m3 = v.w + xrv.w;
            m0 = m0 > 0.f ? m0 : SLOPE * m0;
            m1 = m1 > 0.f ? m1 : SLOPE * m1;
            m2 = m2 > 0.f ? m2 : SLOPE * m2;
            m3 = m3 > 0.f ? m3 : SLOPE * m3;
            float p = m0 * atv.x + m1 * atv.y + m2 * atv.z + m3 * atv.w;
            // reduce over the 8 lanes of this head group (within half-wave)
            p += __shfl_xor(p, 1);
            p += __shfl_xor(p, 2);
            p += __shfl_xor(p, 4);
            float e = (eidx < cnt) ? __expf(p) : 0.f;
            a0 += e * v.x; a1 += e * v.y;
            a2 += e * v.z; a3 += e * v.w;
            den += e;
        }
    }

    // combine the two half-wave accumulators (same channels, different edges)
    a0 += __shfl_xor(a0, 32);
    a1 += __shfl_xor(a1, 32);
    a2 += __shfl_xor(a2, 32);
    a3 += __shfl_xor(a3, 32);
    den += __shfl_xor(den, 32);

    if (sub == 0) {
        float inv = 1.f / (den + 1e-16f);
        float4 bv = *(const float4*)(bias + c0);
        float4 o;
        o.x = fmaxf(a0 * inv + bv.x, 0.f);
        o.y = fmaxf(a1 * inv + bv.y, 0.f);
        o.z = fmaxf(a2 * inv + bv.z, 0.f);
        o.w = fmaxf(a3 * inv + bv.w, 0.f);
        *(float4*)(out + (size_t)n * DF + c0) = o;
    }
}

// ---------------------------------------------------------------------------
extern "C" void kernel_launch(void* const* d_in, const int* in_sizes, int n_in,
                              void* d_out, int out_size, void* d_ws, size_t ws_size,
                              hipStream_t stream)
{
    (void)in_sizes; (void)n_in; (void)out_size; (void)ws_size;

    const float* x    = (const float*)d_in[0];
    const int*   ei   = (const int*)d_in[1];
    const float* W1l  = (const float*)d_in[2];
    const float* W1r  = (const float*)d_in[3];
    const float* att1 = (const float*)d_in[4];
    const float* b1   = (const float*)d_in[5];
    const float* W2l  = (const float*)d_in[6];
    const float* W2r  = (const float*)d_in[7];
    const float* att2 = (const float*)d_in[8];
    const float* b2   = (const float*)d_in[9];
    float* out = (float*)d_out;

    char* ws = (char*)d_ws;
    size_t off = 0;
    const size_t NF = (size_t)N_NODES * DF * sizeof(float);   // 25.6 MB
    float* A  = (float*)(ws + off); off += NF;                // xl
    float* B  = (float*)(ws + off); off += NF;                // xr
    float* C  = (float*)(ws + off); off += NF;                // layer-1 output h
    int* counts  = (int*)(ws + off); off += (size_t)N_NODES * sizeof(int);
    int* row_ptr = (int*)(ws + off); off += (size_t)(N_NODES + 1) * sizeof(int);
    int* cursor  = (int*)(ws + off); off += (size_t)N_NODES * sizeof(int);
    int* csr_src = (int*)(ws + off); off += (size_t)ET * sizeof(int);

    // ---- CSR over dst (shared by both layers) ----
    hipMemsetAsync(counts, 0, (size_t)N_NODES * sizeof(int), stream);
    hist_kernel<<<(ET + 255) / 256, 256, 0, stream>>>(ei, counts);
    scan_kernel<<<1, 1024, 0, stream>>>(counts, row_ptr, cursor);
    scatter_kernel<<<(ET + 255) / 256, 256, 0, stream>>>(ei, cursor, csr_src);

    dim3 gg((N_NODES + 63) / 64, 4);

    // ---- layer 1 ----
    gemm_dual<<<gg, 256, 0, stream>>>(x, W1l, W1r, A, B, N_NODES);
    fused_agg<<<(N_NODES + 3) / 4, 256, 0, stream>>>(A, B, row_ptr, csr_src, att1, b1, C);

    // ---- layer 2 ----
    gemm_dual<<<gg, 256, 0, stream>>>(C, W2l, W2r, A, B, N_NODES);
    fused_agg<<<(N_NODES + 3) / 4, 256, 0, stream>>>(A, B, row_ptr, csr_src, att2, b2, out);
}

// Round 4
// 442.813 us; speedup vs baseline: 2.9039x; 1.5872x over previous
//
#include <hip/hip_runtime.h>

#define N_NODES 50000
#define N_EDGES 1600000
#define ET (N_EDGES + N_NODES)   // edges + self-loops
#define DF 128                   // feature / hidden dim
#define SLOPE 0.2f

#define NB 196        // coarse buckets: dst >> 8 (50000/256)
#define BCAP 10240    // slots per bucket (avg 8448, sigma ~92 -> +19 sigma)
#define P1_CHUNK 4096 // edges per bin_pass block (16 per thread)

// ---------------------------------------------------------------------------
// Dual GEMM: outL = X @ Wl, outR = X @ Wr.  X: [M,128], W: [128,128].
// Tile 64 rows x 64 cols, 256 threads, 4x4 micro-tile, BK=32.
// blockIdx.y in [0,4): 0,1 -> Wl cols 0-63/64-127 ; 2,3 -> Wr.
// ---------------------------------------------------------------------------
__global__ __launch_bounds__(256) void gemm_dual(
    const float* __restrict__ X,
    const float* __restrict__ Wl, const float* __restrict__ Wr,
    float* __restrict__ outL, float* __restrict__ outR, int M)
{
    const int which = blockIdx.y;
    const float* W = (which < 2) ? Wl : Wr;
    float* out = (which < 2) ? outL : outR;
    const int cb = (which & 1) * 64;

    __shared__ float xs[32][68];   // x tile transposed: xs[k][row]
    __shared__ float wsh[32][68];  // w tile: wsh[k][col]

    const int t  = threadIdx.x;
    const int tx = t & 15, ty = t >> 4;
    const int row0 = blockIdx.x * 64;

    float acc[4][4];
#pragma unroll
    for (int i = 0; i < 4; i++)
#pragma unroll
        for (int j = 0; j < 4; j++) acc[i][j] = 0.f;

    const int lr = t >> 2;        // 0..63 : row within tile for x load
    const int lk = (t & 3) * 8;   // k octet base for x load (0,8,16,24)
    const int wk = t >> 4;        // 0..15 : k (and k+16) for W load
    const int wc = (t & 15) * 4;  // col quad for W load

    for (int kb = 0; kb < 128; kb += 32) {
        int xrw = row0 + lr; if (xrw >= M) xrw = M - 1;   // clamp; store is guarded
        float4 xv0 = *(const float4*)(X + (size_t)xrw * DF + kb + lk);
        float4 xv1 = *(const float4*)(X + (size_t)xrw * DF + kb + lk + 4);
        xs[lk + 0][lr] = xv0.x; xs[lk + 1][lr] = xv0.y;
        xs[lk + 2][lr] = xv0.z; xs[lk + 3][lr] = xv0.w;
        xs[lk + 4][lr] = xv1.x; xs[lk + 5][lr] = xv1.y;
        xs[lk + 6][lr] = xv1.z; xs[lk + 7][lr] = xv1.w;

        float4 wv0 = *(const float4*)(W + (size_t)(kb + wk) * DF + cb + wc);
        float4 wv1 = *(const float4*)(W + (size_t)(kb + wk + 16) * DF + cb + wc);
        *(float4*)(&wsh[wk][wc])      = wv0;
        *(float4*)(&wsh[wk + 16][wc]) = wv1;
        __syncthreads();
#pragma unroll
        for (int kk = 0; kk < 32; kk++) {
            float4 a = *(const float4*)(&xs[kk][ty * 4]);
            float4 b = *(const float4*)(&wsh[kk][tx * 4]);
            float av[4] = {a.x, a.y, a.z, a.w};
            float bv[4] = {b.x, b.y, b.z, b.w};
#pragma unroll
            for (int i = 0; i < 4; i++)
#pragma unroll
                for (int j = 0; j < 4; j++)
                    acc[i][j] += av[i] * bv[j];
        }
        __syncthreads();
    }
#pragma unroll
    for (int i = 0; i < 4; i++) {
        int r = row0 + ty * 4 + i;
        if (r < M) {
            float4 v = make_float4(acc[i][0], acc[i][1], acc[i][2], acc[i][3]);
            *(float4*)(out + (size_t)r * DF + cb + tx * 4) = v;
        }
    }
}

// ---------------------------------------------------------------------------
// CSR build, two-level bucket sort.
// Pass 1: bin edges by coarse bucket (dst>>8). Packed 4B: src | (dst&255)<<16.
// Block-local LDS histogram -> one global atomicAdd per bucket per block ->
// run-structured writes (L2-merge friendly).
// ---------------------------------------------------------------------------
__global__ __launch_bounds__(256) void bin_pass(const int* __restrict__ ei,
                                                int* __restrict__ g_count,
                                                int* __restrict__ bucket_mem)
{
    __shared__ int cnt[NB], base[NB], cnt2[NB];
    const int tid = threadIdx.x;
    for (int i = tid; i < NB; i += 256) { cnt[i] = 0; cnt2[i] = 0; }
    __syncthreads();

    const int e0 = blockIdx.x * P1_CHUNK;
    int srcv[16], dstv[16];
#pragma unroll
    for (int i = 0; i < 16; i++) {
        int eid = e0 + i * 256 + tid;   // coalesced
        int s = 0, d = -1;
        if (eid < ET) {
            if (eid < N_EDGES) { s = ei[eid]; d = ei[N_EDGES + eid]; }
            else               { s = d = eid - N_EDGES; }
        }
        srcv[i] = s; dstv[i] = d;
        if (d >= 0) atomicAdd(&cnt[d >> 8], 1);
    }
    __syncthreads();
    for (int i = tid; i < NB; i += 256)
        base[i] = (cnt[i] > 0) ? atomicAdd(&g_count[i], cnt[i]) : 0;
    __syncthreads();
#pragma unroll
    for (int i = 0; i < 16; i++) {
        int d = dstv[i];
        if (d >= 0) {
            int b = d >> 8;
            int r = atomicAdd(&cnt2[b], 1);
            int slot = base[b] + r;
            if (slot < BCAP)
                bucket_mem[(size_t)b * BCAP + slot] =
                    (srcv[i] & 0xFFFF) | ((d & 255) << 16);
        }
    }
}

// Exclusive scan over the NB bucket counts (single tiny block).
__global__ __launch_bounds__(256) void bucket_scan(const int* __restrict__ g_count,
                                                   int* __restrict__ bucket_base)
{
    __shared__ int v[256];
    int tid = threadIdx.x;
    int c = (tid < NB) ? g_count[tid] : 0;
    v[tid] = c; __syncthreads();
    for (int d = 1; d < 256; d <<= 1) {
        int x = (tid >= d) ? v[tid - d] : 0;
        __syncthreads();
        v[tid] += x;
        __syncthreads();
    }
    if (tid < NB) bucket_base[tid] = v[tid] - c;
}

// Pass 2: one block per bucket. LDS-stage edges, local 256-node hist + scan
// (produces row_ptr directly), then scatter csr_src into the bucket's
// contiguous region (block-private -> full-line L2 writebacks).
__global__ __launch_bounds__(256) void csr_pass(const int* __restrict__ g_count,
                                                const int* __restrict__ bucket_base,
                                                const int* __restrict__ bucket_mem,
                                                int* __restrict__ row_ptr,
                                                int* __restrict__ csr_src)
{
    __shared__ int sh_edges[BCAP];
    __shared__ int hist[256], offs[256], excl[256], cnt2[256];
    const int b = blockIdx.x, tid = threadIdx.x;
    int m = g_count[b]; if (m > BCAP) m = BCAP;
    hist[tid] = 0; cnt2[tid] = 0;
    __syncthreads();
    const int* bm = bucket_mem + (size_t)b * BCAP;
    for (int i = tid; i < m; i += 256) {
        int p = bm[i];
        sh_edges[i] = p;
        atomicAdd(&hist[(p >> 16) & 255], 1);
    }
    __syncthreads();
    offs[tid] = hist[tid]; __syncthreads();
    for (int d = 1; d < 256; d <<= 1) {
        int x = (tid >= d) ? offs[tid - d] : 0;
        __syncthreads();
        offs[tid] += x;
        __syncthreads();
    }
    excl[tid] = offs[tid] - hist[tid];
    const int node0 = b << 8;
    const int base_csr = bucket_base[b];
    if (node0 + tid < N_NODES) row_ptr[node0 + tid] = base_csr + excl[tid];
    if (b == 0 && tid == 0) row_ptr[N_NODES] = ET;
    __syncthreads();
    for (int i = tid; i < m; i += 256) {
        int p = sh_edges[i];
        int dl = (p >> 16) & 255;
        int r = atomicAdd(&cnt2[dl], 1);
        csr_src[base_csr + excl[dl] + r] = p & 0xFFFF;
    }
}

// ---------------------------------------------------------------------------
// Fused scores + softmax + aggregate: one wave per dst node, 2 edges/iter.
// Half-wave (32 lanes) per edge; lane covers 4 channels (float4); head = li/8.
// ---------------------------------------------------------------------------
__global__ __launch_bounds__(256) void fused_agg(
    const float* __restrict__ xl, const float* __restrict__ xr,
    const int* __restrict__ row_ptr, const int* __restrict__ csr_src,
    const float* __restrict__ att, const float* __restrict__ bias,
    float* __restrict__ out)
{
    int t = threadIdx.x;
    int wave = t >> 6, l = t & 63;
    int sub = l >> 5, li = l & 31;          // half-wave id, lane within half
    int n = blockIdx.x * 4 + wave;
    if (n >= N_NODES) return;
    int beg = row_ptr[n], end = row_ptr[n + 1];

    const int c0 = 4 * li;
    float4 xrv = *(const float4*)(xr + (size_t)n * DF + c0);
    float4 atv = *(const float4*)(att + c0);

    float a0 = 0.f, a1 = 0.f, a2 = 0.f, a3 = 0.f, den = 0.f;

    for (int base = beg; base < end; base += 64) {
        int cnt = end - base; if (cnt > 64) cnt = 64;
        int my_src = 0;
        if (base + l < end) my_src = csr_src[base + l];   // coalesced batch load
        int npair = (cnt + 1) >> 1;
        for (int j = 0; j < npair; j++) {
            int eidx = 2 * j + sub;                       // edge slot for my half
            int s = __shfl(my_src, eidx);
            float4 v = *(const float4*)(xl + (size_t)s * DF + c0);
            float m0 = v.x + xrv.x, m1 = v.y + xrv.y;
            float m2 = v.z + xrv.z, m3 = v.w + xrv.w;
            m0 = m0 > 0.f ? m0 : SLOPE * m0;
            m1 = m1 > 0.f ? m1 : SLOPE * m1;
            m2 = m2 > 0.f ? m2 : SLOPE * m2;
            m3 = m3 > 0.f ? m3 : SLOPE * m3;
            float p = m0 * atv.x + m1 * atv.y + m2 * atv.z + m3 * atv.w;
            p += __shfl_xor(p, 1);
            p += __shfl_xor(p, 2);
            p += __shfl_xor(p, 4);
            float e = (eidx < cnt) ? __expf(p) : 0.f;
            a0 += e * v.x; a1 += e * v.y;
            a2 += e * v.z; a3 += e * v.w;
            den += e;
        }
    }

    a0 += __shfl_xor(a0, 32);
    a1 += __shfl_xor(a1, 32);
    a2 += __shfl_xor(a2, 32);
    a3 += __shfl_xor(a3, 32);
    den += __shfl_xor(den, 32);

    if (sub == 0) {
        float inv = 1.f / (den + 1e-16f);
        float4 bv = *(const float4*)(bias + c0);
        float4 o;
        o.x = fmaxf(a0 * inv + bv.x, 0.f);
        o.y = fmaxf(a1 * inv + bv.y, 0.f);
        o.z = fmaxf(a2 * inv + bv.z, 0.f);
        o.w = fmaxf(a3 * inv + bv.w, 0.f);
        *(float4*)(out + (size_t)n * DF + c0) = o;
    }
}

// ---------------------------------------------------------------------------
extern "C" void kernel_launch(void* const* d_in, const int* in_sizes, int n_in,
                              void* d_out, int out_size, void* d_ws, size_t ws_size,
                              hipStream_t stream)
{
    (void)in_sizes; (void)n_in; (void)out_size; (void)ws_size;

    const float* x    = (const float*)d_in[0];
    const int*   ei   = (const int*)d_in[1];
    const float* W1l  = (const float*)d_in[2];
    const float* W1r  = (const float*)d_in[3];
    const float* att1 = (const float*)d_in[4];
    const float* b1   = (const float*)d_in[5];
    const float* W2l  = (const float*)d_in[6];
    const float* W2r  = (const float*)d_in[7];
    const float* att2 = (const float*)d_in[8];
    const float* b2   = (const float*)d_in[9];
    float* out = (float*)d_out;

    char* ws = (char*)d_ws;
    size_t off = 0;
    const size_t NF = (size_t)N_NODES * DF * sizeof(float);   // 25.6 MB
    float* A  = (float*)(ws + off); off += NF;                // xl
    float* B  = (float*)(ws + off); off += NF;                // xr
    float* C  = (float*)(ws + off); off += NF;                // layer-1 output h
    int* bucket_mem  = (int*)(ws + off); off += (size_t)NB * BCAP * sizeof(int);
    int* g_count     = (int*)(ws + off); off += 256 * sizeof(int);
    int* bucket_base = (int*)(ws + off); off += 256 * sizeof(int);
    int* row_ptr     = (int*)(ws + off); off += (size_t)(N_NODES + 1) * sizeof(int);
    int* csr_src     = (int*)(ws + off); off += (size_t)ET * sizeof(int);

    // ---- CSR over dst (shared by both layers) ----
    hipMemsetAsync(g_count, 0, NB * sizeof(int), stream);
    bin_pass<<<(ET + P1_CHUNK - 1) / P1_CHUNK, 256, 0, stream>>>(ei, g_count, bucket_mem);
    bucket_scan<<<1, 256, 0, stream>>>(g_count, bucket_base);
    csr_pass<<<NB, 256, 0, stream>>>(g_count, bucket_base, bucket_mem, row_ptr, csr_src);

    dim3 gg((N_NODES + 63) / 64, 4);

    // ---- layer 1 ----
    gemm_dual<<<gg, 256, 0, stream>>>(x, W1l, W1r, A, B, N_NODES);
    fused_agg<<<(N_NODES + 3) / 4, 256, 0, stream>>>(A, B, row_ptr, csr_src, att1, b1, C);

    // ---- layer 2 ----
    gemm_dual<<<gg, 256, 0, stream>>>(C, W2l, W2r, A, B, N_NODES);
    fused_agg<<<(N_NODES + 3) / 4, 256, 0, stream>>>(A, B, row_ptr, csr_src, att2, b2, out);
}